// Round 10
// baseline (1081.114 us; speedup 1.0000x reference)
//
#include <hip/hip_runtime.h>

typedef unsigned short u16;
typedef unsigned int u32;
typedef __attribute__((ext_vector_type(8))) _Float16 half8;
typedef __attribute__((ext_vector_type(4))) float floatx4;
typedef __attribute__((ext_vector_type(4))) u32 uintx4;

// ---------------- helpers ----------------
__device__ __forceinline__ u16 f2h(float f) {
  union { _Float16 h; u16 u; } v; v.h = (_Float16)f; return v.u;
}
__device__ __forceinline__ float h2f(u16 u) {
  union { u16 u; _Float16 h; } v; v.u = u; return (float)v.h;
}

// ---------------- ws layout (bytes) ----------------
// Weights packed in MFMA-FRAGMENT order:
//   [kt][nt][kk][lane][8]; n = nt*16+(lane&15), k = kk*32+(lane>>4)*8+j,
//   c = (kt&3)*64 + k, tap = kt>>2.
static constexpr size_t OFF_XP   = 0;         // [32][36][36][256] f16
static constexpr size_t OFF_YMID = 21233664;  // [32][34][34][256] f16
static constexpr size_t OFF_OFFB = 40173568;  // [32768][64] f32
static constexpr size_t OFF_WB1  = 48562176;  // 36*16*2*64*8 f16 frag-order
static constexpr size_t OFF_WBO  = 49741824;  // 36*4*2*64*8
static constexpr size_t OFF_WB3  = 50036736;  // 100*16*2*64*8
static constexpr size_t OFF_WB2  = 53313536;  // 36*16*2*64*8
static constexpr size_t OFF_BNP  = 54493184;  // [6][256] f32

// ---------------- zero fill ----------------
__global__ __launch_bounds__(256) void zero_kernel(uintx4* __restrict__ p, int n) {
  int i = blockIdx.x * 256 + threadIdx.x;
  if (i < n) { uintx4 z = {0u, 0u, 0u, 0u}; p[i] = z; }
}

// ---------------- pack weights (fragment-order) + bn params ----------------
__global__ __launch_bounds__(256) void prep_kernel(
    const float* __restrict__ w1, const float* __restrict__ woff,
    const float* __restrict__ w3, const float* __restrict__ w2,
    const float* __restrict__ g1, const float* __restrict__ b1,
    const float* __restrict__ m1, const float* __restrict__ v1,
    const float* __restrict__ g3, const float* __restrict__ b3,
    const float* __restrict__ m3, const float* __restrict__ v3,
    const float* __restrict__ g2, const float* __restrict__ b2,
    const float* __restrict__ m2, const float* __restrict__ v2,
    u16* __restrict__ wB1, u16* __restrict__ wBo,
    u16* __restrict__ wB3, u16* __restrict__ wB2,
    float* __restrict__ bnp)
{
  int i = blockIdx.x * 256 + threadIdx.x;
  if (i < 589824) {                    // wB1f [kt=36][nt=16][kk=2][lane][j]
    int j = i & 7, lane = (i >> 3) & 63, kk = (i >> 9) & 1;
    int nt = (i >> 10) & 15, kt = i >> 14;
    int n = nt * 16 + (lane & 15);
    int c = ((kt & 3) << 6) + kk * 32 + ((lane >> 4) << 3) + j;
    wB1[i] = f2h(w1[(n * 256 + c) * 9 + (kt >> 2)]);
    return;
  }
  i -= 589824;
  if (i < 147456) {                    // wBof [kt=36][nt=4][kk=2][lane][j]
    int j = i & 7, lane = (i >> 3) & 63, kk = (i >> 9) & 1;
    int nt = (i >> 10) & 3, kt = i >> 12;
    int n = nt * 16 + (lane & 15);
    int c = ((kt & 3) << 6) + kk * 32 + ((lane >> 4) << 3) + j;
    wBo[i] = (n < 50) ? f2h(woff[(n * 256 + c) * 9 + (kt >> 2)]) : (u16)0;
    return;
  }
  i -= 147456;
  if (i < 1638400) {                   // wB3f [kt=100][nt=16][kk=2][lane][j]
    int j = i & 7, lane = (i >> 3) & 63, kk = (i >> 9) & 1;
    int nt = (i >> 10) & 15, kt = i >> 14;
    int n = nt * 16 + (lane & 15);
    int c = ((kt & 3) << 6) + kk * 32 + ((lane >> 4) << 3) + j;
    wB3[i] = f2h(w3[(n * 256 + c) * 25 + (kt >> 2)]);
    return;
  }
  i -= 1638400;
  if (i < 589824) {                    // wB2f
    int j = i & 7, lane = (i >> 3) & 63, kk = (i >> 9) & 1;
    int nt = (i >> 10) & 15, kt = i >> 14;
    int n = nt * 16 + (lane & 15);
    int c = ((kt & 3) << 6) + kk * 32 + ((lane >> 4) << 3) + j;
    wB2[i] = f2h(w2[(n * 256 + c) * 9 + (kt >> 2)]);
    return;
  }
  i -= 589824;
  if (i < 1536) {                      // bn params
    int grp = i >> 8, n = i & 255;
    const float* g  = (grp < 2) ? g1 : (grp < 4) ? g3 : g2;
    const float* bb = (grp < 2) ? b1 : (grp < 4) ? b3 : b2;
    const float* mm = (grp < 2) ? m1 : (grp < 4) ? m3 : m2;
    const float* vv = (grp < 2) ? v1 : (grp < 4) ? v3 : v2;
    float sc = g[n] / sqrtf(vv[n] + 1e-5f);
    bnp[i] = (grp & 1) ? (bb[n] - mm[n] * sc) : sc;
  }
}

// ---------------- pack x: NCHW f32 -> NHWC f16 border-2 ----------------
__global__ __launch_bounds__(256) void pack_x_kernel(const float* __restrict__ x,
                                                     u16* __restrict__ xp)
{
  __shared__ float trans[256][33];
  int b = blockIdx.x >> 5, y = blockIdx.x & 31;
  int t = threadIdx.x;
  int xi = t & 31, ch = t >> 5;
  const float* src = x + (b * 256 * 1024) + y * 32 + xi;
#pragma unroll 4
  for (int c8 = 0; c8 < 32; ++c8) {
    int c = c8 * 8 + ch;
    trans[c][xi] = src[c * 1024];
  }
  __syncthreads();
  u16* dstrow = xp + ((b * 36 + y + 2) * 36 + 2) * 256 + t;
#pragma unroll 4
  for (int xx = 0; xx < 32; ++xx)
    dstrow[xx * 256] = f2h(trans[t][xx]);
}

// ---------------- barrier-free strip conv (3x3) ----------------
// Each wave owns a 16-row M-strip x full N: A-fragment loaded DIRECTLY from
// NHWC global (m=lane&15 -> own row; k-chunk=(lane>>4)*8), B fragments from
// frag-packed global (L1-hot: same 32KB/phase across all resident waves).
// NO LDS, NO __syncthreads in the K-loop — pure streaming, 16 indep acc chains.
template <int EPI, int NTW, int WPAD>
__global__ __launch_bounds__(256, 4) void conv_strip_kernel(
    const u16* __restrict__ img, const u16* __restrict__ wB,
    const float* __restrict__ p0, const float* __restrict__ p1,
    const float* __restrict__ xorig, void* __restrict__ dst)
{
  constexpr int BRD = (WPAD - 34) / 2;
  const int t = threadIdx.x;
  const int wave = t >> 6, lane = t & 63;
  const int phys = blockIdx.x;
  const int mStrip = ((phys & 7) * 64 + (phys >> 3)) * 64 + wave * 16; // XCD swz
  const int mrow = mStrip + (lane & 15);
  const int b = mrow >> 10, y = (mrow >> 5) & 31, x = mrow & 31;
  const u16* abase = img + ((b * WPAD + y + BRD) * WPAD + (x + BRD)) * 256
                         + ((lane >> 4) << 3);
  const u16* wfrag = wB + lane * 8;

  floatx4 acc[NTW] = {};
  // software-prefetched A fragment (registers only; no sync needed)
  half8 a0 = *(const half8*)(abase);
  half8 a1 = *(const half8*)(abase + 32);

  for (int kt = 0; kt < 36; ++kt) {
    half8 ac0 = a0, ac1 = a1;
    {
      const int ktp = (kt < 35) ? kt + 1 : 35;
      const int tap = ktp >> 2, c0 = (ktp & 3) << 6;
      const int kh = tap / 3, kw = tap - kh * 3;
      const u16* p = abase + (kh * WPAD + kw) * 256 + c0;
      a0 = *(const half8*)(p);
      a1 = *(const half8*)(p + 32);
    }
#pragma unroll
    for (int ni = 0; ni < NTW; ++ni) {
      half8 b0 = *(const half8*)(wfrag + (((kt * NTW + ni) * 2 + 0) << 9));
      half8 b1 = *(const half8*)(wfrag + (((kt * NTW + ni) * 2 + 1) << 9));
      acc[ni] = __builtin_amdgcn_mfma_f32_16x16x32_f16(ac0, b0, acc[ni], 0, 0, 0);
      acc[ni] = __builtin_amdgcn_mfma_f32_16x16x32_f16(ac1, b1, acc[ni], 0, 0, 0);
    }
  }

#pragma unroll
  for (int ni = 0; ni < NTW; ++ni) {
    const int n = ni * 16 + (lane & 15);
    float sc = 0.f, bi = 0.f;
    if constexpr (EPI == 0 || EPI == 2) { sc = p0[n]; bi = p1[n]; }
    else { sc = (n < 50) ? p0[n] : 0.f; }
    const int mb = mStrip + ((lane >> 4) << 2);
    if constexpr (EPI == 0) {
      u16* ym = (u16*)dst;
#pragma unroll
      for (int r = 0; r < 4; ++r) {
        int m = mb + r;
        int bb2 = m >> 10, yy = (m >> 5) & 31, xx = m & 31;
        float v = fmaxf(acc[ni][r] * sc + bi, 0.f);
        ym[((bb2 * 34 + yy + 1) * 34 + (xx + 1)) * 256 + n] = f2h(v);
      }
    } else if constexpr (EPI == 1) {
      float* ob = (float*)dst;
#pragma unroll
      for (int r = 0; r < 4; ++r)
        ob[(mb + r) * 64 + n] = acc[ni][r] + sc;
    } else {
      int bb2 = mb >> 10, s = mb & 1023;
      const float* xr = xorig + ((bb2 * 256 + n) << 10) + s;
      float* orow = (float*)dst + ((bb2 * 256 + n) << 10) + s;
      floatx4 xv = *(const floatx4*)xr;
      floatx4 res;
#pragma unroll
      for (int r = 0; r < 4; ++r)
        res[r] = fmaxf(acc[ni][r] * sc + bi + xv[r], 0.f);
      *(floatx4*)orow = res;
    }
  }
}

// ---------------- barrier-free strip deformable conv ----------------
struct Geo { float w00, w01, w10, w11; int base; };

__device__ __forceinline__ Geo mkgeo(int soh, int sow, int ti, int tj, float2 ov) {
  float py = (float)(soh - 2 + ti) + ov.x;
  float px = (float)(sow - 2 + tj) + ov.y;
  // zero-outside bilinear == clamp into [-1,32] vs border-2 zero-padded image
  py = fminf(32.f, fmaxf(-1.f, py));
  px = fminf(32.f, fmaxf(-1.f, px));
  float fy = floorf(py), fx = floorf(px);
  float wy1 = py - fy, wx1 = px - fx;
  float wy0 = 1.f - wy1, wx0 = 1.f - wx1;
  Geo g;
  g.w00 = wy0 * wx0; g.w01 = wy0 * wx1; g.w10 = wy1 * wx0; g.w11 = wy1 * wx1;
  g.base = (((int)fy + 2) * 36 + ((int)fx + 2)) * 256;
  return g;
}

// Each wave: 16-row strip x N=256, acc[16]. Bilinear blend goes STRAIGHT into
// the MFMA A-fragment register (m=lane&15 -> own row, k-chunk=(lane>>4)*8):
// per-row sampling count identical to the LDS version (4 lanes/row), but zero
// LDS and zero barriers — waves free-run and hide each other's load latency.
__global__ __launch_bounds__(256, 4) void deform_kernel(
    const u16* __restrict__ xp, const u16* __restrict__ wBf,
    const float* __restrict__ offb,
    const float* __restrict__ sc3, const float* __restrict__ bi3,
    u16* __restrict__ ymid)
{
  const int t = threadIdx.x;
  const int wave = t >> 6, lane = t & 63;
  const int phys = blockIdx.x;
  const int mStrip = ((phys & 7) * 64 + (phys >> 3)) * 64 + wave * 16; // XCD swz
  const int mrow = mStrip + (lane & 15);
  const int sb = mrow >> 10, soh = (mrow >> 5) & 31, sow = mrow & 31;
  const u16* ximg = xp + sb * (36 * 36 * 256) + ((lane >> 4) << 3);
  const float2* offrow = (const float2*)(offb + mrow * 64);
  const u16* wfrag = wBf + lane * 8;

  floatx4 acc[16] = {};

  for (int tap = 0; tap < 25; ++tap) {
    const int ti = tap / 5, tj = tap - ti * 5;
    const Geo g = mkgeo(soh, sow, ti, tj, offrow[tap]);
    const _Float16 h00 = (_Float16)g.w00, h01 = (_Float16)g.w01;
    const _Float16 h10 = (_Float16)g.w10, h11 = (_Float16)g.w11;
    const u16* pb0 = ximg + g.base;
#pragma unroll
    for (int cc = 0; cc < 4; ++cc) {
      const int kt = tap * 4 + cc;
      half8 af[2];
#pragma unroll
      for (int kk = 0; kk < 2; ++kk) {
        const u16* p = pb0 + cc * 64 + kk * 32;
        half8 c00 = *(const half8*)(p);
        half8 c01 = *(const half8*)(p + 256);
        half8 c10 = *(const half8*)(p + 9216);
        half8 c11 = *(const half8*)(p + 9472);
        af[kk] = c00 * h00 + c01 * h01 + c10 * h10 + c11 * h11;
      }
#pragma unroll
      for (int ni = 0; ni < 16; ++ni) {
        half8 b0 = *(const half8*)(wfrag + (((kt * 16 + ni) * 2 + 0) << 9));
        half8 b1 = *(const half8*)(wfrag + (((kt * 16 + ni) * 2 + 1) << 9));
        acc[ni] = __builtin_amdgcn_mfma_f32_16x16x32_f16(af[0], b0, acc[ni], 0, 0, 0);
        acc[ni] = __builtin_amdgcn_mfma_f32_16x16x32_f16(af[1], b1, acc[ni], 0, 0, 0);
      }
    }
  }

#pragma unroll
  for (int ni = 0; ni < 16; ++ni) {
    const int n = ni * 16 + (lane & 15);
    float sc = sc3[n], bi = bi3[n];
    const int mb = mStrip + ((lane >> 4) << 2);
#pragma unroll
    for (int r = 0; r < 4; ++r) {
      int m = mb + r;
      int b = m >> 10, yy = (m >> 5) & 31, xx = m & 31;
      int idx = ((b * 34 + yy + 1) * 34 + (xx + 1)) * 256 + n;
      float v = fmaxf(acc[ni][r] * sc + bi, 0.f) + h2f(ymid[idx]);
      ymid[idx] = f2h(v);
    }
  }
}

// ---------------- launch ----------------
extern "C" void kernel_launch(void* const* d_in, const int* in_sizes, int n_in,
                              void* d_out, int out_size, void* d_ws, size_t ws_size,
                              hipStream_t stream)
{
  const float* x    = (const float*)d_in[0];
  const float* w1   = (const float*)d_in[1];
  const float* woff = (const float*)d_in[2];
  const float* boff = (const float*)d_in[3];
  const float* w3   = (const float*)d_in[4];
  const float* w2   = (const float*)d_in[5];
  const float* g1 = (const float*)d_in[6],  *b1 = (const float*)d_in[7];
  const float* m1 = (const float*)d_in[8],  *v1 = (const float*)d_in[9];
  const float* g3 = (const float*)d_in[10], *b3 = (const float*)d_in[11];
  const float* m3 = (const float*)d_in[12], *v3 = (const float*)d_in[13];
  const float* g2 = (const float*)d_in[14], *b2 = (const float*)d_in[15];
  const float* m2 = (const float*)d_in[16], *v2 = (const float*)d_in[17];

  char* ws = (char*)d_ws;
  u16*   xp   = (u16*)(ws + OFF_XP);
  u16*   ymid = (u16*)(ws + OFF_YMID);
  float* offb = (float*)(ws + OFF_OFFB);
  u16*   wB1  = (u16*)(ws + OFF_WB1);
  u16*   wBo  = (u16*)(ws + OFF_WBO);
  u16*   wB3  = (u16*)(ws + OFF_WB3);
  u16*   wB2  = (u16*)(ws + OFF_WB2);
  float* bnp  = (float*)(ws + OFF_BNP);

  zero_kernel<<<9808, 256, 0, stream>>>((uintx4*)ws, 2510848);
  prep_kernel<<<11590, 256, 0, stream>>>(w1, woff, w3, w2,
                                         g1, b1, m1, v1, g3, b3, m3, v3,
                                         g2, b2, m2, v2,
                                         wB1, wBo, wB3, wB2, bnp);
  pack_x_kernel<<<1024, 256, 0, stream>>>(x, xp);
  // offset conv (N=64 padded, +b_off) -> offb
  conv_strip_kernel<1, 4, 36><<<512, 256, 0, stream>>>(
      xp, wBo, boff, nullptr, nullptr, (void*)offb);
  // conv1 + bn1 + relu -> ymid
  conv_strip_kernel<0, 16, 36><<<512, 256, 0, stream>>>(
      xp, wB1, bnp + 0, bnp + 256, nullptr, (void*)ymid);
  // deform conv + bn3 + relu, accumulate into ymid
  deform_kernel<<<512, 256, 0, stream>>>(xp, wB3, offb, bnp + 512, bnp + 768, ymid);
  // conv2 + bn2 + residual + relu -> out (f32 NCHW)
  conv_strip_kernel<2, 16, 34><<<512, 256, 0, stream>>>(
      ymid, wB2, bnp + 1024, bnp + 1280, x, d_out);
}